// Round 1
// baseline (206.662 us; speedup 1.0000x reference)
//
#include <hip/hip_runtime.h>
#include <hip/hip_bf16.h>

// Problem constants (from reference): B=1024, S=200, IN1=IN2=H=128
constexpr int S_ = 200;
constexpr int SP = 208;   // padded S = 13 * 16

typedef __attribute__((ext_vector_type(8))) short short8_t;
typedef __attribute__((ext_vector_type(4))) float float4_t;

__device__ inline unsigned short f2bf(float f) {
  unsigned int u = __float_as_uint(f);
  u += 0x7FFFu + ((u >> 16) & 1u);      // round-to-nearest-even
  return (unsigned short)(u >> 16);
}
__device__ inline float bf2f(unsigned int us) {
  return __uint_as_float(us << 16);
}

__global__ __launch_bounds__(256, 2) void m2o_attn_kernel(
    const float* __restrict__ input, const float* __restrict__ z,
    const int* __restrict__ mask, const float* __restrict__ W1,
    const float* __restrict__ W2, const float* __restrict__ b2,
    const float* __restrict__ V, const float* __restrict__ bV,
    float* __restrict__ out) {
  __shared__ __align__(16) unsigned short in_lds[SP * 128];  // bf16, XOR-swizzled rows
  __shared__ float att_part[4][SP];
  __shared__ float w2h_lds[128];
  __shared__ float att_w[SP];
  __shared__ float pool[4][128];
  __shared__ float redA[4], redB[4];

  const int t = threadIdx.x;
  const int b = blockIdx.x;
  const int lane = t & 63;
  const int wid = t >> 6;

  // ---- stage input[b] -> LDS bf16, swizzle: ushort idx ^= (row&7)<<3 (16B granule) ----
  const float4* inp4 = reinterpret_cast<const float4*>(input + (size_t)b * (S_ * 128));
  #pragma unroll
  for (int i = 0; i < 25; ++i) {
    int f = t + i * 256;                 // float4 index 0..6399
    float4 v = inp4[f];
    int s = f >> 5;                      // 32 float4 per row
    int d0 = (f & 31) << 2;
    int idx = s * 128 + (d0 ^ ((s & 7) << 3));
    unsigned int lo = (unsigned int)f2bf(v.x) | ((unsigned int)f2bf(v.y) << 16);
    unsigned int hi = (unsigned int)f2bf(v.z) | ((unsigned int)f2bf(v.w) << 16);
    *reinterpret_cast<uint2*>(&in_lds[idx]) = make_uint2(lo, hi);
  }
  // zero pad rows 200..207
  {
    unsigned int* p32 = reinterpret_cast<unsigned int*>(in_lds);
    for (int i = t; i < 8 * 64; i += 256) p32[200 * 64 + i] = 0u;
  }
  // ---- w2h = z[b] @ W2 + b2 (threads 0..127, f32 exact) ----
  if (t < 128) {
    float acc = b2[t];
    const float* zb = z + (size_t)b * 128;
    for (int d = 0; d < 128; ++d) acc += zb[d] * W2[d * 128 + t];
    w2h_lds[t] = acc;
  }
  // ---- preload W1 B-fragments into registers (wave owns cols [32*wid, 32*wid+32)) ----
  const int hb = wid * 32;
  short8_t bfrag[2][4];
  #pragma unroll
  for (int n = 0; n < 2; ++n) {
    int h = hb + n * 16 + (lane & 15);
    #pragma unroll
    for (int kk = 0; kk < 4; ++kk) {
      short8_t fr;
      #pragma unroll
      for (int j = 0; j < 8; ++j) {
        int k = (lane >> 4) * 8 + j + kk * 32;
        fr[j] = (short)f2bf(W1[k * 128 + h]);
      }
      bfrag[n][kk] = fr;
    }
  }
  const float v0 = V[hb + (lane & 15)];
  const float v1 = V[hb + 16 + (lane & 15)];

  __syncthreads();

  const float w0 = w2h_lds[hb + (lane & 15)];
  const float w1v = w2h_lds[hb + 16 + (lane & 15)];

  // ---- main loop: w1h tiles + fused tanh + V-dot ----
  for (int mt = 0; mt < 13; ++mt) {
    float4_t acc0 = {0.f, 0.f, 0.f, 0.f};
    float4_t acc1 = {0.f, 0.f, 0.f, 0.f};
    const int arow = mt * 16 + (lane & 15);
    const int swz = (arow & 7) << 3;
    #pragma unroll
    for (int kk = 0; kk < 4; ++kk) {
      const int k0 = (lane >> 4) * 8 + kk * 32;
      const short8_t a = *reinterpret_cast<const short8_t*>(
          &in_lds[arow * 128 + (k0 ^ swz)]);
      acc0 = __builtin_amdgcn_mfma_f32_16x16x32_bf16(a, bfrag[0][kk], acc0, 0, 0, 0);
      acc1 = __builtin_amdgcn_mfma_f32_16x16x32_bf16(a, bfrag[1][kk], acc1, 0, 0, 0);
    }
    // D layout: col h = ntile*16 + (lane&15); row s = mt*16 + (lane>>4)*4 + r
    #pragma unroll
    for (int r = 0; r < 4; ++r) {
      float x0 = fminf(10.f, fmaxf(-10.f, acc0[r] + w0));
      float x1 = fminf(10.f, fmaxf(-10.f, acc1[r] + w1v));
      float t0 = __expf(2.f * x0);
      float t1 = __expf(2.f * x1);
      float u0 = 1.f - __fdividef(2.f, t0 + 1.f);
      float u1 = 1.f - __fdividef(2.f, t1 + 1.f);
      float p = u0 * v0 + u1 * v1;
      p += __shfl_xor(p, 1);
      p += __shfl_xor(p, 2);
      p += __shfl_xor(p, 4);
      p += __shfl_xor(p, 8);
      if ((lane & 15) == 0)
        att_part[wid][mt * 16 + (lane >> 4) * 4 + r] = p;
    }
  }
  __syncthreads();

  // ---- masked softmax over S ----
  float logit = -3.0e38f, e = 0.f;
  {
    float val;
    if (t < S_) {
      val = att_part[0][t] + att_part[1][t] + att_part[2][t] + att_part[3][t] + bV[0];
      if (mask[(size_t)b * S_ + t] == 0) val = -1e10f;
    } else {
      val = -3.0e38f;
    }
    logit = val;
    float m = val;
    #pragma unroll
    for (int off = 32; off; off >>= 1) m = fmaxf(m, __shfl_xor(m, off));
    if (lane == 0) redA[wid] = m;
  }
  __syncthreads();
  {
    float M = fmaxf(fmaxf(redA[0], redA[1]), fmaxf(redA[2], redA[3]));
    e = (t < S_) ? __expf(logit - M) : 0.f;
    float sg = e;
    #pragma unroll
    for (int off = 32; off; off >>= 1) sg += __shfl_xor(sg, off);
    if (lane == 0) redB[wid] = sg;
  }
  __syncthreads();
  {
    float Ssum = redB[0] + redB[1] + redB[2] + redB[3];
    if (t < SP) att_w[t] = (t < S_) ? e / Ssum : 0.f;
  }
  __syncthreads();

  // ---- pooling: out[b][d] = sum_s att_w[s] * input_bf16[b][s][d] (from LDS) ----
  {
    const unsigned int* l32 = reinterpret_cast<const unsigned int*>(in_lds);
    const int p = t & 63;    // dword column (d = 2p, 2p+1)
    const int c = t >> 6;    // s-chunk of 50
    float a0 = 0.f, a1 = 0.f;
    for (int s = c * 50; s < c * 50 + 50; ++s) {
      float w = att_w[s];
      unsigned int u = l32[s * 64 + (p ^ ((s & 7) << 2))];
      a0 += w * bf2f(u & 0xffffu);
      a1 += w * bf2f(u >> 16);
    }
    pool[c][2 * p] = a0;
    pool[c][2 * p + 1] = a1;
  }
  __syncthreads();
  if (t < 128)
    out[(size_t)b * 128 + t] = pool[0][t] + pool[1][t] + pool[2][t] + pool[3][t];
}

extern "C" void kernel_launch(void* const* d_in, const int* in_sizes, int n_in,
                              void* d_out, int out_size, void* d_ws, size_t ws_size,
                              hipStream_t stream) {
  const float* input = (const float*)d_in[0];
  const float* z     = (const float*)d_in[1];
  const int*   mask  = (const int*)d_in[2];
  const float* W1    = (const float*)d_in[3];
  const float* W2    = (const float*)d_in[4];
  const float* b2    = (const float*)d_in[5];
  const float* V     = (const float*)d_in[6];
  const float* bV    = (const float*)d_in[7];
  float* out = (float*)d_out;
  m2o_attn_kernel<<<1024, 256, 0, stream>>>(input, z, mask, W1, W2, b2, V, bV, out);
}

// Round 3
// 196.244 us; speedup vs baseline: 1.0531x; 1.0531x over previous
//
#include <hip/hip_runtime.h>
#include <hip/hip_bf16.h>

// Problem constants: B=1024, S=200, IN1=IN2=H=128
constexpr int S_ = 200;
constexpr int SP = 208;

typedef __attribute__((ext_vector_type(8))) short short8_t;
typedef __attribute__((ext_vector_type(4))) float float4_t;

__device__ inline unsigned short f2bf(float f) {
  unsigned int u = __float_as_uint(f);
  u += 0x7FFFu + ((u >> 16) & 1u);   // RTE
  return (unsigned short)(u >> 16);
}
__device__ inline unsigned int pk2(float x, float y) {
  return (unsigned int)f2bf(x) | ((unsigned int)f2bf(y) << 16);
}

__global__ __launch_bounds__(256, 4) void m2o_attn_kernel(
    const float* __restrict__ input, const float* __restrict__ z,
    const int* __restrict__ mask, const float* __restrict__ W1,
    const float* __restrict__ W2, const float* __restrict__ b2,
    const float* __restrict__ V, const float* __restrict__ bV,
    float* __restrict__ out) {
  __shared__ float w2h_part[2][128];
  __shared__ float att_part[2][SP];
  __shared__ float att_w[SP];
  __shared__ float pool[2][128];
  __shared__ float redA[4], redB[4];

  const int t = threadIdx.x;
  const int b = blockIdx.x;
  const int lane = t & 63;
  const int wid = t >> 6;
  const int c = lane & 15;      // MFMA col / A-row lane
  const int kb = lane >> 4;     // k-block 0..3

  const float* inb = input + (size_t)b * (S_ * 128);

  // hoist mask + bV into registers (hide latency under the compute below)
  const int maskv = (t < S_) ? mask[(size_t)b * S_ + t] : 0;
  const float bVv = bV[0];

  // ---- w2h partials: all 256 threads, thread t = (half ph of K) x (col h) ----
  {
    const int h = t & 127, ph = t >> 7;
    const float* zb = z + (size_t)b * 128 + ph * 64;
    float acc = (ph == 0) ? b2[h] : 0.f;
    #pragma unroll 8
    for (int d = 0; d < 64; ++d) acc = fmaf(zb[d], W2[(ph * 64 + d) * 128 + h], acc);
    w2h_part[ph][h] = acc;
  }

  // ---- W1 B-fragments direct from global (L2-resident), wave owns 64 h-cols ----
  const int hh = (wid & 1) * 64;
  short8_t bfrag[4][4];
  #pragma unroll
  for (int n = 0; n < 4; ++n) {
    const int h = hh + n * 16 + c;
    #pragma unroll
    for (int kk = 0; kk < 4; ++kk) {
      union { short8_t s8; unsigned int u[4]; } cv;
      #pragma unroll
      for (int jp = 0; jp < 4; ++jp) {
        const int k = kk * 32 + kb * 8 + jp * 2;
        cv.u[jp] = pk2(W1[k * 128 + h], W1[(k + 1) * 128 + h]);
      }
      bfrag[n][kk] = cv.s8;
    }
  }
  float vv[4];
  #pragma unroll
  for (int n = 0; n < 4; ++n) vv[n] = V[hh + n * 16 + c];

  __syncthreads();

  float w2v[4];
  #pragma unroll
  for (int n = 0; n < 4; ++n) {
    const int h = hh + n * 16 + c;
    w2v[n] = w2h_part[0][h] + w2h_part[1][h];
  }

  // ---- main loop: wave handles (row-half) x (h-half); A from global w/ prefetch ----
  const int half = wid >> 1;
  const int pslot = wid & 1;
  const int mt0 = half * 7;
  const int nmt = half ? 6 : 7;

  float4 pa[4][2];
  {
    const int arow = mt0 * 16 + c;
    const int lrow = arow < S_ ? arow : (S_ - 1);
    const float* rp = inb + lrow * 128 + kb * 8;
    #pragma unroll
    for (int kk = 0; kk < 4; ++kk) {
      pa[kk][0] = *reinterpret_cast<const float4*>(rp + kk * 32);
      pa[kk][1] = *reinterpret_cast<const float4*>(rp + kk * 32 + 4);
    }
  }

  for (int i = 0; i < nmt; ++i) {
    const int mt = mt0 + i;
    // convert prefetched A to bf16 frags
    short8_t a[4];
    #pragma unroll
    for (int kk = 0; kk < 4; ++kk) {
      union { short8_t s8; unsigned int u[4]; } cv;
      cv.u[0] = pk2(pa[kk][0].x, pa[kk][0].y);
      cv.u[1] = pk2(pa[kk][0].z, pa[kk][0].w);
      cv.u[2] = pk2(pa[kk][1].x, pa[kk][1].y);
      cv.u[3] = pk2(pa[kk][1].z, pa[kk][1].w);
      a[kk] = cv.s8;
    }
    // prefetch next mt tile
    if (i + 1 < nmt) {
      const int arow = (mt + 1) * 16 + c;
      const int lrow = arow < S_ ? arow : (S_ - 1);
      const float* rp = inb + lrow * 128 + kb * 8;
      #pragma unroll
      for (int kk = 0; kk < 4; ++kk) {
        pa[kk][0] = *reinterpret_cast<const float4*>(rp + kk * 32);
        pa[kk][1] = *reinterpret_cast<const float4*>(rp + kk * 32 + 4);
      }
    }
    float4_t acc[4] = {{0.f, 0.f, 0.f, 0.f}, {0.f, 0.f, 0.f, 0.f},
                       {0.f, 0.f, 0.f, 0.f}, {0.f, 0.f, 0.f, 0.f}};
    #pragma unroll
    for (int kk = 0; kk < 4; ++kk) {
      #pragma unroll
      for (int n = 0; n < 4; ++n)
        acc[n] = __builtin_amdgcn_mfma_f32_16x16x32_bf16(a[kk], bfrag[n][kk], acc[n], 0, 0, 0);
    }
    // fused tanh + V-dot epilogue; D layout: col = n*16+c, row = mt*16 + kb*4 + r
    #pragma unroll
    for (int r = 0; r < 4; ++r) {
      const int row = mt * 16 + kb * 4 + r;
      float p = 0.f;
      #pragma unroll
      for (int n = 0; n < 4; ++n) {
        const float x = acc[n][r] + w2v[n];
        const float e = __expf(x + x);            // inf-safe: u -> +/-1
        const float u = 1.f - __fdividef(2.f, e + 1.f);
        p = fmaf(u, vv[n], p);
      }
      p += __shfl_xor(p, 1);
      p += __shfl_xor(p, 2);
      p += __shfl_xor(p, 4);
      p += __shfl_xor(p, 8);
      if (c == 0 && row < S_) att_part[pslot][row] = p;
    }
  }
  __syncthreads();

  // ---- masked softmax over S ----
  float logit = -3.0e38f, ee = 0.f;
  if (t < S_) {
    logit = att_part[0][t] + att_part[1][t] + bVv;
    if (maskv == 0) logit = -1e10f;
  }
  {
    float m = logit;
    #pragma unroll
    for (int off = 32; off; off >>= 1) m = fmaxf(m, __shfl_xor(m, off));
    if (lane == 0) redA[wid] = m;
  }
  __syncthreads();
  {
    const float M = fmaxf(fmaxf(redA[0], redA[1]), fmaxf(redA[2], redA[3]));
    ee = (t < S_) ? __expf(logit - M) : 0.f;
    float sg = ee;
    #pragma unroll
    for (int off = 32; off; off >>= 1) sg += __shfl_xor(sg, off);
    if (lane == 0) redB[wid] = sg;
  }
  __syncthreads();
  {
    const float Ssum = redB[0] + redB[1] + redB[2] + redB[3];
    if (t < SP) att_w[t] = (t < S_) ? __fdividef(ee, Ssum) : 0.f;
  }
  __syncthreads();

  // ---- pooling: out[b][d] = sum_s att_w[s] * input[b][s][d] (global, L2/L3-hit) ----
  {
    const int d = t & 127, ph = t >> 7;
    const float* pp = inb + (size_t)(ph * 100) * 128 + d;
    float a0 = 0.f;
    #pragma unroll 4
    for (int s = 0; s < 100; ++s) a0 = fmaf(att_w[ph * 100 + s], pp[s * 128], a0);
    pool[ph][d] = a0;
  }
  __syncthreads();
  if (t < 128) out[(size_t)b * 128 + t] = pool[0][t] + pool[1][t];
}

extern "C" void kernel_launch(void* const* d_in, const int* in_sizes, int n_in,
                              void* d_out, int out_size, void* d_ws, size_t ws_size,
                              hipStream_t stream) {
  const float* input = (const float*)d_in[0];
  const float* z     = (const float*)d_in[1];
  const int*   mask  = (const int*)d_in[2];
  const float* W1    = (const float*)d_in[3];
  const float* W2    = (const float*)d_in[4];
  const float* b2    = (const float*)d_in[5];
  const float* V     = (const float*)d_in[6];
  const float* bV    = (const float*)d_in[7];
  float* out = (float*)d_out;
  m2o_attn_kernel<<<1024, 256, 0, stream>>>(input, z, mask, W1, W2, b2, V, bV, out);
}